// Round 5
// baseline (438.211 us; speedup 1.0000x reference)
//
#include <hip/hip_runtime.h>
#include <cstdint>
#include <cmath>

#define T_TOK 1024
#define H_DIM 1024
#define E_NUM 32
#define I_DIM 512
#define IS_DIM 2048
#define NCOL_R 16384
#define NCOL_T 18432
#define SCALE_F 2.5f
#define MAXTILES 96

typedef __bf16 bf16x8 __attribute__((ext_vector_type(8)));
typedef float f32x4 __attribute__((ext_vector_type(4)));

typedef __attribute__((address_space(3))) unsigned int lds_u32_t;
typedef __attribute__((address_space(1))) const unsigned int glb_u32_t;

__device__ __forceinline__ unsigned short f2b(float f) {
    union { float f; uint32_t u; } v; v.f = f;
    return (unsigned short)((v.u + 0x7FFFu + ((v.u >> 16) & 1u)) >> 16);
}

__device__ __forceinline__ void gll16(const unsigned short* g, unsigned short* l) {
    __builtin_amdgcn_global_load_lds((glb_u32_t*)g, (lds_u32_t*)l, 16, 0, 0);
}

// ---------------- X fp32 -> bf16 ----------------
__global__ void cvt_x_kernel(const float* __restrict__ x, unsigned short* __restrict__ xb) {
    int i = blockIdx.x * 256 + threadIdx.x;
    float4 v = reinterpret_cast<const float4*>(x)[i];
    uint2 o;
    o.x = (uint32_t)f2b(v.x) | ((uint32_t)f2b(v.y) << 16);
    o.y = (uint32_t)f2b(v.z) | ((uint32_t)f2b(v.w) << 16);
    reinterpret_cast<uint2*>(xb)[i] = o;
}

// ---------------- weight fp32 [R][C] tile -> bf16 transposed dst[c][r] ----------------
__device__ __forceinline__ void tcvt_tile(const float* __restrict__ s, unsigned short* __restrict__ dst,
                                          int C, int DS, int r0, int c0, int t, float* tile /*64*68*/) {
    int lr = t >> 4, lc4 = (t & 15) * 4;
#pragma unroll
    for (int p = 0; p < 4; p++) {
        float4 v = *reinterpret_cast<const float4*>(s + (size_t)(r0 + lr + p * 16) * C + c0 + lc4);
        *reinterpret_cast<float4*>(&tile[(lr + p * 16) * 68 + lc4]) = v;
    }
    __syncthreads();
    int oc = t >> 2, orr = (t & 3) * 16;
    uint32_t o[8];
#pragma unroll
    for (int j = 0; j < 8; j++)
        o[j] = (uint32_t)f2b(tile[(orr + 2 * j) * 68 + oc]) | ((uint32_t)f2b(tile[(orr + 2 * j + 1) * 68 + oc]) << 16);
    unsigned short* dp = dst + (size_t)(c0 + oc) * DS + r0 + orr;
    uint4 u0; u0.x = o[0]; u0.y = o[1]; u0.z = o[2]; u0.w = o[3];
    uint4 u1; u1.x = o[4]; u1.y = o[5]; u1.z = o[6]; u1.w = o[7];
    *reinterpret_cast<uint4*>(dp) = u0;
    *reinterpret_cast<uint4*>(dp + 8) = u1;
}

// all 6 weight conversions in one dispatch (13824 blocks)
__global__ __launch_bounds__(256)
void tcvt_all(const float* __restrict__ w_gate, const float* __restrict__ w_up,
              const float* __restrict__ ws_gate, const float* __restrict__ ws_up,
              const float* __restrict__ w_down, const float* __restrict__ ws_down,
              unsigned short* __restrict__ BG, unsigned short* __restrict__ BU,
              unsigned short* __restrict__ SG, unsigned short* __restrict__ SU,
              unsigned short* __restrict__ BDs, unsigned short* __restrict__ BSD) {
    __shared__ float tile[64 * 68];
    int b = blockIdx.x, t = threadIdx.x;
    const float* src; unsigned short* dst; int C, DS, r0, c0;
    if (b < 4096) {
        int local = b & 127, e = b >> 7;
        r0 = (local & 15) * 64; c0 = (local >> 4) * 64;
        src = w_gate + (size_t)e * 524288; dst = BG + (size_t)e * 524288; C = 512; DS = 1024;
    } else if (b < 8192) {
        int bb = b - 4096, local = bb & 127, e = bb >> 7;
        r0 = (local & 15) * 64; c0 = (local >> 4) * 64;
        src = w_up + (size_t)e * 524288; dst = BU + (size_t)e * 524288; C = 512; DS = 1024;
    } else if (b < 8704) {
        int local = b - 8192;
        r0 = (local & 15) * 64; c0 = (local >> 4) * 64;
        src = ws_gate; dst = SG; C = 2048; DS = 1024;
    } else if (b < 9216) {
        int local = b - 8704;
        r0 = (local & 15) * 64; c0 = (local >> 4) * 64;
        src = ws_up; dst = SU; C = 2048; DS = 1024;
    } else if (b < 13312) {
        int bb = b - 9216, local = bb & 127, e = bb >> 7;
        r0 = (local & 7) * 64; c0 = (local >> 3) * 64;
        src = w_down + (size_t)e * 524288; dst = BDs + (size_t)e * 524288; C = 1024; DS = 512;
    } else {
        int local = b - 13312;
        r0 = (local & 31) * 64; c0 = (local >> 5) * 64;
        src = ws_down; dst = BSD; C = 1024; DS = 2048;
    }
    tcvt_tile(src, dst, C, DS, r0, c0, t, tile);
}

// ---------------- routing: 1 wave = 1 token, 4 tokens/block ----------------
__global__ __launch_bounds__(256)
void routing_kernel(const float* __restrict__ x,
                    const float* __restrict__ gate_w,
                    const float* __restrict__ e_bias,
                    float* __restrict__ combine,
                    int* __restrict__ topk) {
    __shared__ float red[4][64 * 33];       // 33.8 KB
    __shared__ float sscore[4][32], sswb[4][32];
    int w = threadIdx.x >> 6, l = threadIdx.x & 63;
    int t = blockIdx.x * 4 + w;

    float xv[16];
    const float* xp = x + (size_t)t * H_DIM + l;
#pragma unroll
    for (int i = 0; i < 16; i++) xv[i] = xp[i * 64];
#pragma unroll 4
    for (int e = 0; e < 32; e++) {
        const float* wrow = gate_w + (size_t)e * H_DIM + l;
        float s = 0.f;
#pragma unroll
        for (int i = 0; i < 16; i++) s = fmaf(xv[i], wrow[i * 64], s);
        red[w][l * 33 + e] = s;
    }
    __syncthreads();
    if (l < 32) {
        float lg = 0.f;
#pragma unroll 8
        for (int j = 0; j < 64; j++) lg += red[w][j * 33 + l];
        float sg = 1.f / (1.f + expf(-lg));
        sscore[w][l] = sg;
        sswb[w][l] = sg + e_bias[l];
    }
    __syncthreads();
    if (l == 0) {
        float sc[32], sb[32];
#pragma unroll
        for (int e = 0; e < 32; e++) { sc[e] = sscore[w][e]; sb[e] = sswb[w][e]; }
        // group scores: top-2 sum per group of 4 (all static-indexed -> registers)
        float gs[8];
#pragma unroll
        for (int g = 0; g < 8; g++) {
            float a0 = sb[4*g], a1 = sb[4*g+1], a2 = sb[4*g+2], a3 = sb[4*g+3];
            float hi01 = fmaxf(a0,a1), lo01 = fminf(a0,a1);
            float hi23 = fmaxf(a2,a3), lo23 = fminf(a2,a3);
            gs[g] = fmaxf(hi01, hi23) + fmaxf(fminf(hi01, hi23), fmaxf(lo01, lo23));
        }
        unsigned gm = 0;
#pragma unroll
        for (int it = 0; it < 4; it++) {
            int bi = 0; float bv = -1e30f;
#pragma unroll
            for (int g = 0; g < 8; g++)
                if (!((gm >> g) & 1) && gs[g] > bv) { bv = gs[g]; bi = g; }
            gm |= 1u << bi;
        }
        float cand[32];
#pragma unroll
        for (int e = 0; e < 32; e++) cand[e] = ((gm >> (e >> 2)) & 1) ? sb[e] : 0.0f;
        unsigned em = 0;
#pragma unroll
        for (int it = 0; it < 8; it++) {
            int bi = 0; float bv = -1e30f;
#pragma unroll
            for (int e = 0; e < 32; e++)
                if (!((em >> e) & 1) && cand[e] > bv) { bv = cand[e]; bi = e; }
            em |= 1u << bi;
            topk[t * 8 + it] = bi;
        }
        float ssum = 0.f;
#pragma unroll
        for (int e = 0; e < 32; e++) if ((em >> e) & 1) ssum += sc[e];
        float inv = SCALE_F / (ssum + 1e-20f);
#pragma unroll
        for (int e = 0; e < 32; e++)
            combine[t * E_NUM + e] = ((em >> e) & 1) ? sc[e] * inv : 0.0f;
    }
}

// ---------------- build expert segments (single block, 1024 threads) ----------------
__global__ __launch_bounds__(1024)
void listbuild_kernel(const int* __restrict__ topk, int* __restrict__ meta,
                      int* __restrict__ pair_token, int* __restrict__ slot_of) {
    __shared__ int cnt[E_NUM], start[E_NUM], fill[E_NUM];
    int t = threadIdx.x;
    if (t < E_NUM) cnt[t] = 0;
    __syncthreads();
    int ids[8];
#pragma unroll
    for (int r = 0; r < 8; r++) {
        ids[r] = topk[t * 8 + r];
        atomicAdd(&cnt[ids[r]], 1);
    }
    __syncthreads();
    if (t == 0) {
        int acc = 0;
        for (int e = 0; e < E_NUM; e++) {
            int nt = (cnt[e] + 127) >> 7;
            start[e] = acc * 128;
            fill[e] = 0;
            for (int j = 0; j < nt; j++) meta[1 + acc + j] = e;
            acc += nt;
        }
        meta[0] = acc;
    }
    __syncthreads();
    for (int i = t; i < MAXTILES * 128; i += 1024) pair_token[i] = 0;
    __syncthreads();
#pragma unroll
    for (int r = 0; r < 8; r++) {
        int e = ids[r];
        int s = start[e] + atomicAdd(&fill[e], 1);
        pair_token[s] = t;
        slot_of[t * 8 + r] = s;
    }
}

// ---------------- unified gate/up: routed tiles + shared expert ----------------
// blocks [0, MAXTILES*4): routed; [MAXTILES*4, MAXTILES*4+128): shared
__global__ __launch_bounds__(256, 2)
void gateup_u(const unsigned short* __restrict__ xb,
              const unsigned short* __restrict__ BG,   // [e*512+i][h]
              const unsigned short* __restrict__ BU,
              const unsigned short* __restrict__ SG,   // [is][h]
              const unsigned short* __restrict__ SU,
              const float* __restrict__ combine,
              const int* __restrict__ pair_token,
              const int* __restrict__ meta,
              unsigned short* __restrict__ act_s,
              unsigned short* __restrict__ act_sh) {
    int b = blockIdx.x;
    bool routed = b < MAXTILES * 4;
    int tile = 0, e = 0, ci0 = 0, slot0 = 0, row0 = 0, c0 = 0;
    if (routed) {
        tile = b >> 2;
        if (tile >= meta[0]) return;
        e = meta[1 + tile];
        ci0 = (b & 3) * 128;
        slot0 = tile * 128;
    } else {
        int s2 = b - MAXTILES * 4;
        row0 = (s2 >> 4) * 128;
        c0 = (s2 & 15) * 128;
    }
    __shared__ __align__(16) unsigned short lA[128*32];
    __shared__ __align__(16) unsigned short lBg[128*32];
    __shared__ __align__(16) unsigned short lBu[128*32];
    int tid = threadIdx.x, lane = tid & 63, w = tid >> 6;
    int wr = w >> 1, wc = w & 1;
    f32x4 accg[4][4], accu[4][4];
#pragma unroll
    for (int i = 0; i < 4; i++)
#pragma unroll
        for (int j = 0; j < 4; j++)
#pragma unroll
            for (int r = 0; r < 4; r++) { accg[i][j][r] = 0.f; accu[i][j][r] = 0.f; }

    int srow = w * 32 + (lane >> 2);
    int schunk = (lane & 3) * 8;
    const unsigned short *gA0, *gA1, *gG0, *gU0;
    if (routed) {
        int tok0 = pair_token[slot0 + srow];
        int tok1 = pair_token[slot0 + srow + 16];
        gA0 = xb + (size_t)tok0 * H_DIM + schunk;
        gA1 = xb + (size_t)tok1 * H_DIM + schunk;
        int brow0 = e * I_DIM + ci0;
        gG0 = BG + (size_t)(brow0 + srow) * H_DIM + schunk;
        gU0 = BU + (size_t)(brow0 + srow) * H_DIM + schunk;
    } else {
        gA0 = xb + (size_t)(row0 + srow) * H_DIM + schunk;
        gA1 = gA0 + 16 * H_DIM;
        gG0 = SG + (size_t)(c0 + srow) * H_DIM + schunk;
        gU0 = SU + (size_t)(c0 + srow) * H_DIM + schunk;
    }
    unsigned short* lA0 = &lA[(w * 32) * 32];
    unsigned short* lG0 = &lBg[(w * 32) * 32];
    unsigned short* lU0 = &lBu[(w * 32) * 32];

    for (int kk = 0; kk < H_DIM / 32; kk++) {
        int k0 = kk * 32;
        __syncthreads();
        gll16(gA0 + k0, lA0);
        gll16(gA1 + k0, lA0 + 16 * 32);
        gll16(gG0 + k0, lG0);
        gll16(gG0 + 16 * H_DIM + k0, lG0 + 16 * 32);
        gll16(gU0 + k0, lU0);
        gll16(gU0 + 16 * H_DIM + k0, lU0 + 16 * 32);
        __syncthreads();
        bf16x8 af[4], bgf[4], buf2[4];
#pragma unroll
        for (int mi = 0; mi < 4; mi++)
            af[mi] = *reinterpret_cast<const bf16x8*>(&lA[(wr*64 + mi*16 + (lane & 15))*32 + (lane >> 4)*8]);
#pragma unroll
        for (int ni = 0; ni < 4; ni++) {
            int nn = (wc*64 + ni*16 + (lane & 15))*32 + (lane >> 4)*8;
            bgf[ni]  = *reinterpret_cast<const bf16x8*>(&lBg[nn]);
            buf2[ni] = *reinterpret_cast<const bf16x8*>(&lBu[nn]);
        }
#pragma unroll
        for (int mi = 0; mi < 4; mi++)
#pragma unroll
            for (int ni = 0; ni < 4; ni++) {
                accg[mi][ni] = __builtin_amdgcn_mfma_f32_16x16x32_bf16(af[mi], bgf[ni],  accg[mi][ni], 0, 0, 0);
                accu[mi][ni] = __builtin_amdgcn_mfma_f32_16x16x32_bf16(af[mi], buf2[ni], accu[mi][ni], 0, 0, 0);
            }
    }
    int q = lane >> 4, cl = lane & 15;
    if (routed) {
#pragma unroll
        for (int mi = 0; mi < 4; mi++) {
#pragma unroll
            for (int r = 0; r < 4; r++) {
                int row = wr*64 + mi*16 + q*4 + r;
                int token = pair_token[slot0 + row];
                float s = combine[token * E_NUM + e];
#pragma unroll
                for (int ni = 0; ni < 4; ni++) {
                    float g = accg[mi][ni][r], u = accu[mi][ni][r];
                    float a = g / (1.f + expf(-g)) * u * s;
                    act_s[(size_t)(slot0 + row) * I_DIM + ci0 + wc*64 + ni*16 + cl] = f2b(a);
                }
            }
        }
    } else {
#pragma unroll
        for (int mi = 0; mi < 4; mi++) {
#pragma unroll
            for (int ni = 0; ni < 4; ni++) {
                int col = c0 + wc*64 + ni*16 + cl;
#pragma unroll
                for (int r = 0; r < 4; r++) {
                    int row = row0 + wr*64 + mi*16 + q*4 + r;
                    float g = accg[mi][ni][r], u = accu[mi][ni][r];
                    float a = g / (1.f + expf(-g)) * u;
                    act_sh[(size_t)row * IS_DIM + col] = f2b(a);
                }
            }
        }
    }
}

// ---------------- unified down: routed tiles + shared (split-K=4) ----------------
// blocks [0, MAXTILES*8): routed; [MAXTILES*8, MAXTILES*8+256): shared
__global__ __launch_bounds__(256, 2)
void down_u(const unsigned short* __restrict__ act_s,
            const unsigned short* __restrict__ BDs,   // [e][h][i]
            const unsigned short* __restrict__ act_sh,
            const unsigned short* __restrict__ BSD,   // [h][is]
            const int* __restrict__ meta,
            float* __restrict__ pairpart,
            float* __restrict__ shpart) {
    int b = blockIdx.x;
    bool routed = b < MAXTILES * 8;
    int tid = threadIdx.x, lane = tid & 63, w = tid >> 6;
    int srow = w * 32 + (lane >> 2);
    int schunk = (lane & 3) * 8;
    const unsigned short *gA0, *gB0;
    int sK, rowb, n0;
    float* pout;
    if (routed) {
        int tile = b >> 3;
        if (tile >= meta[0]) return;
        int e = meta[1 + tile];
        n0 = (b & 7) * 128;
        rowb = tile * 128;
        sK = I_DIM;
        gA0 = act_s + (size_t)(rowb + srow) * I_DIM + schunk;
        gB0 = BDs + (size_t)e * H_DIM * I_DIM + (size_t)(n0 + srow) * I_DIM + schunk;
        pout = pairpart;
    } else {
        int s2 = b - MAXTILES * 8;
        int mb = s2 >> 5, nbk = (s2 >> 2) & 7, ks = s2 & 3;
        rowb = mb * 128; n0 = nbk * 128;
        int koff = ks * 512;
        sK = IS_DIM;
        gA0 = act_sh + (size_t)(rowb + srow) * IS_DIM + koff + schunk;
        gB0 = BSD + (size_t)(n0 + srow) * IS_DIM + koff + schunk;
        pout = shpart + ((size_t)ks << 20);
    }
    __shared__ __align__(16) unsigned short lA[128*32];
    __shared__ __align__(16) unsigned short lB[128*32];
    int wr = w >> 1, wc = w & 1;
    f32x4 acc[4][4];
#pragma unroll
    for (int i = 0; i < 4; i++)
#pragma unroll
        for (int j = 0; j < 4; j++)
#pragma unroll
            for (int r = 0; r < 4; r++) acc[i][j][r] = 0.f;

    unsigned short* lA0 = &lA[(w * 32) * 32];
    unsigned short* lB0 = &lB[(w * 32) * 32];

    for (int kk = 0; kk < 16; kk++) {
        int k0 = kk * 32;
        __syncthreads();
        gll16(gA0 + k0, lA0);
        gll16(gA0 + 16 * sK + k0, lA0 + 16 * 32);
        gll16(gB0 + k0, lB0);
        gll16(gB0 + 16 * sK + k0, lB0 + 16 * 32);
        __syncthreads();
        bf16x8 af[4], bf[4];
#pragma unroll
        for (int mi = 0; mi < 4; mi++)
            af[mi] = *reinterpret_cast<const bf16x8*>(&lA[(wr*64 + mi*16 + (lane & 15))*32 + (lane >> 4)*8]);
#pragma unroll
        for (int ni = 0; ni < 4; ni++)
            bf[ni] = *reinterpret_cast<const bf16x8*>(&lB[(wc*64 + ni*16 + (lane & 15))*32 + (lane >> 4)*8]);
#pragma unroll
        for (int mi = 0; mi < 4; mi++)
#pragma unroll
            for (int ni = 0; ni < 4; ni++)
                acc[mi][ni] = __builtin_amdgcn_mfma_f32_16x16x32_bf16(af[mi], bf[ni], acc[mi][ni], 0, 0, 0);
    }
    int q = lane >> 4, cl = lane & 15;
#pragma unroll
    for (int mi = 0; mi < 4; mi++) {
#pragma unroll
        for (int ni = 0; ni < 4; ni++) {
            int col = n0 + wc*64 + ni*16 + cl;
#pragma unroll
            for (int r = 0; r < 4; r++) {
                int row = rowb + wr*64 + mi*16 + q*4 + r;
                pout[(size_t)row * H_DIM + col] = acc[mi][ni][r];
            }
        }
    }
}

// ---------------- final combine ----------------
__global__ void final_combine(const float* __restrict__ pairpart,
                              const float* __restrict__ shpart,
                              const int* __restrict__ slot_of,
                              float* __restrict__ out) {
    int t = blockIdx.x;
    int h = threadIdx.x * 4;
    float4 o = reinterpret_cast<const float4*>(shpart + (size_t)t * H_DIM + h)[0];
#pragma unroll
    for (int ks = 1; ks < 4; ks++) {
        float4 v = reinterpret_cast<const float4*>(shpart + ((size_t)ks << 20) + (size_t)t * H_DIM + h)[0];
        o.x += v.x; o.y += v.y; o.z += v.z; o.w += v.w;
    }
#pragma unroll
    for (int r = 0; r < 8; r++) {
        int s = slot_of[t * 8 + r];
        float4 v = reinterpret_cast<const float4*>(pairpart + (size_t)s * H_DIM + h)[0];
        o.x += v.x; o.y += v.y; o.z += v.z; o.w += v.w;
    }
    reinterpret_cast<float4*>(out + (size_t)t * H_DIM + h)[0] = o;
}

// ================= FALLBACK PATH (round-1 kernels, small ws) =================

__global__ __launch_bounds__(256, 2)
void gateup_kernel(const unsigned short* __restrict__ xb,
                   const float* __restrict__ w_gate,
                   const float* __restrict__ w_up,
                   const float* __restrict__ ws_gate,
                   const float* __restrict__ ws_up,
                   const float* __restrict__ combine,
                   unsigned short* __restrict__ act) {
    int mb = blockIdx.x, cb = blockIdx.y;
    int row0 = mb * 128, c0 = cb * 128;
    const float *bg, *bu;
    int bstride, eidx;
    if (c0 < NCOL_R) {
        int e = c0 >> 9, ci = c0 & 511;
        bg = w_gate + (size_t)e * H_DIM * I_DIM + ci;
        bu = w_up   + (size_t)e * H_DIM * I_DIM + ci;
        bstride = I_DIM; eidx = e;
    } else {
        int ci = c0 - NCOL_R;
        bg = ws_gate + ci; bu = ws_up + ci;
        bstride = IS_DIM; eidx = -1;
    }
    __shared__ __align__(16) unsigned short lA[128*32];
    __shared__ __align__(16) unsigned short lBg[128*32];
    __shared__ __align__(16) unsigned short lBu[128*32];
    int tid = threadIdx.x, lane = tid & 63, w = tid >> 6;
    int wr = w >> 1, wc = w & 1;
    f32x4 accg[4][4], accu[4][4];
#pragma unroll
    for (int i = 0; i < 4; i++)
#pragma unroll
        for (int j = 0; j < 4; j++)
#pragma unroll
            for (int r = 0; r < 4; r++) { accg[i][j][r] = 0.f; accu[i][j][r] = 0.f; }
    int ar = tid >> 2, ak = (tid & 3) * 8;
    int bn = tid & 127, bkg = (tid >> 7) * 16;
    for (int kk = 0; kk < H_DIM / 32; kk++) {
        int k0 = kk * 32;
        __syncthreads();
        *reinterpret_cast<uint4*>(&lA[ar*32 + ak]) =
            *reinterpret_cast<const uint4*>(xb + (size_t)(row0 + ar) * H_DIM + k0 + ak);
        *reinterpret_cast<uint4*>(&lA[(ar+64)*32 + ak]) =
            *reinterpret_cast<const uint4*>(xb + (size_t)(row0 + ar + 64) * H_DIM + k0 + ak);
#pragma unroll
        for (int p = 0; p < 4; p++) {
            int kb = bkg + p * 4;
            const float* pg = bg + (size_t)(k0 + kb) * bstride + bn;
            uint2 dg;
            dg.x = (uint32_t)f2b(pg[0])         | ((uint32_t)f2b(pg[bstride])   << 16);
            dg.y = (uint32_t)f2b(pg[2*bstride]) | ((uint32_t)f2b(pg[3*bstride]) << 16);
            *reinterpret_cast<uint2*>(&lBg[bn*32 + kb]) = dg;
            const float* pu = bu + (size_t)(k0 + kb) * bstride + bn;
            uint2 du;
            du.x = (uint32_t)f2b(pu[0])         | ((uint32_t)f2b(pu[bstride])   << 16);
            du.y = (uint32_t)f2b(pu[2*bstride]) | ((uint32_t)f2b(pu[3*bstride]) << 16);
            *reinterpret_cast<uint2*>(&lBu[bn*32 + kb]) = du;
        }
        __syncthreads();
        bf16x8 af[4], bgf[4], buf2[4];
#pragma unroll
        for (int mi = 0; mi < 4; mi++)
            af[mi] = *reinterpret_cast<const bf16x8*>(&lA[(wr*64 + mi*16 + (lane & 15))*32 + (lane >> 4)*8]);
#pragma unroll
        for (int ni = 0; ni < 4; ni++) {
            int nn = (wc*64 + ni*16 + (lane & 15))*32 + (lane >> 4)*8;
            bgf[ni]  = *reinterpret_cast<const bf16x8*>(&lBg[nn]);
            buf2[ni] = *reinterpret_cast<const bf16x8*>(&lBu[nn]);
        }
#pragma unroll
        for (int mi = 0; mi < 4; mi++)
#pragma unroll
            for (int ni = 0; ni < 4; ni++) {
                accg[mi][ni] = __builtin_amdgcn_mfma_f32_16x16x32_bf16(af[mi], bgf[ni],  accg[mi][ni], 0, 0, 0);
                accu[mi][ni] = __builtin_amdgcn_mfma_f32_16x16x32_bf16(af[mi], buf2[ni], accu[mi][ni], 0, 0, 0);
            }
    }
    int q = lane >> 4, cl = lane & 15;
#pragma unroll
    for (int mi = 0; mi < 4; mi++) {
#pragma unroll
        for (int ni = 0; ni < 4; ni++) {
            int colg = c0 + wc*64 + ni*16 + cl;
#pragma unroll
            for (int r = 0; r < 4; r++) {
                int row = row0 + wr*64 + mi*16 + q*4 + r;
                float g = accg[mi][ni][r], u = accu[mi][ni][r];
                float a = g / (1.f + expf(-g)) * u;
                float s = (eidx >= 0) ? combine[row * E_NUM + eidx] : 1.0f;
                act[(size_t)row * NCOL_T + colg] = f2b(a * s);
            }
        }
    }
}

__global__ __launch_bounds__(256, 2)
void down_kernel(const unsigned short* __restrict__ act,
                 const float* __restrict__ w_down,
                 const float* __restrict__ ws_down,
                 float* __restrict__ partials) {
    int mb = blockIdx.x, nb = blockIdx.y, ks = blockIdx.z;
    int row0 = mb * 128, n0 = nb * 128;
    __shared__ __align__(16) unsigned short lA[128*32];
    __shared__ __align__(16) unsigned short lB[128*32];
    int tid = threadIdx.x, lane = tid & 63, w = tid >> 6;
    int wr = w >> 1, wc = w & 1;
    f32x4 acc[4][4];
#pragma unroll
    for (int i = 0; i < 4; i++)
#pragma unroll
        for (int j = 0; j < 4; j++)
#pragma unroll
            for (int r = 0; r < 4; r++) acc[i][j][r] = 0.f;
    int ar = tid >> 2, ak = (tid & 3) * 8;
    int bn = tid & 127, bkg = (tid >> 7) * 16;
    for (int kk = 0; kk < 144; kk++) {
        int k0 = ks * 4608 + kk * 32;
        const float* bb = (k0 < NCOL_R) ? (w_down + (size_t)k0 * H_DIM)
                                        : (ws_down + (size_t)(k0 - NCOL_R) * H_DIM);
        __syncthreads();
        *reinterpret_cast<uint4*>(&lA[ar*32 + ak]) =
            *reinterpret_cast<const uint4*>(act + (size_t)(row0 + ar) * NCOL_T + k0 + ak);
        *reinterpret_cast<uint4*>(&lA[(ar+64)*32 + ak]) =
            *reinterpret_cast<const uint4*>(act + (size_t)(row0 + ar + 64) * NCOL_T + k0 + ak);
#pragma unroll
        for (int p = 0; p < 4; p++) {
            int kb = bkg + p * 4;
            const float* pb = bb + (size_t)kb * H_DIM + n0 + bn;
            uint2 d;
            d.x = (uint32_t)f2b(pb[0])       | ((uint32_t)f2b(pb[H_DIM])   << 16);
            d.y = (uint32_t)f2b(pb[2*H_DIM]) | ((uint32_t)f2b(pb[3*H_DIM]) << 16);
            *reinterpret_cast<uint2*>(&lB[bn*32 + kb]) = d;
        }
        __syncthreads();
        bf16x8 af[4], bf[4];
#pragma unroll
        for (int mi = 0; mi < 4; mi++)
            af[mi] = *reinterpret_cast<const bf16x8*>(&lA[(wr*64 + mi*16 + (lane & 15))*32 + (lane >> 4)*8]);
#pragma unroll
        for (int ni = 0; ni < 4; ni++)
            bf[ni] = *reinterpret_cast<const bf16x8*>(&lB[(wc*64 + ni*16 + (lane & 15))*32 + (lane >> 4)*8]);
#pragma unroll
        for (int mi = 0; mi < 4; mi++)
#pragma unroll
            for (int ni = 0; ni < 4; ni++)
                acc[mi][ni] = __builtin_amdgcn_mfma_f32_16x16x32_bf16(af[mi], bf[ni], acc[mi][ni], 0, 0, 0);
    }
    float* pout = partials + ((size_t)ks << 20);
    int q = lane >> 4, cl = lane & 15;
#pragma unroll
    for (int mi = 0; mi < 4; mi++) {
#pragma unroll
        for (int ni = 0; ni < 4; ni++) {
            int col = n0 + wc*64 + ni*16 + cl;
#pragma unroll
            for (int r = 0; r < 4; r++) {
                int row = row0 + wr*64 + mi*16 + q*4 + r;
                pout[(size_t)row * H_DIM + col] = acc[mi][ni][r];
            }
        }
    }
}

__global__ void reduce_kernel(const float* __restrict__ p, float* __restrict__ out) {
    int i = blockIdx.x * 256 + threadIdx.x;
    float4 a = reinterpret_cast<const float4*>(p)[i];
    float4 b = reinterpret_cast<const float4*>(p + (size_t)1048576)[i];
    float4 c = reinterpret_cast<const float4*>(p + (size_t)2097152)[i];
    float4 d = reinterpret_cast<const float4*>(p + (size_t)3145728)[i];
    float4 o;
    o.x = a.x + b.x + c.x + d.x;
    o.y = a.y + b.y + c.y + d.y;
    o.z = a.z + b.z + c.z + d.z;
    o.w = a.w + b.w + c.w + d.w;
    reinterpret_cast<float4*>(out)[i] = o;
}

extern "C" void kernel_launch(void* const* d_in, const int* in_sizes, int n_in,
                              void* d_out, int out_size, void* d_ws, size_t ws_size,
                              hipStream_t stream) {
    const float* x       = (const float*)d_in[0];
    const float* gate_w  = (const float*)d_in[1];
    const float* e_bias  = (const float*)d_in[2];
    const float* w_gate  = (const float*)d_in[3];
    const float* w_up    = (const float*)d_in[4];
    const float* w_down  = (const float*)d_in[5];
    const float* ws_gate = (const float*)d_in[6];
    const float* ws_up   = (const float*)d_in[7];
    const float* ws_down = (const float*)d_in[8];
    float* out = (float*)d_out;

    char* ws = (char*)d_ws;
    bool fast = ws_size >= 170000384ull;   // ws_size constant across calls -> capture-safe branch

    if (fast) {
        float* combine      = (float*)(ws);                       // 131072
        int*   topk         = (int*)(ws + 131072);                // 32768
        int*   meta         = (int*)(ws + 163840);                // 512
        int*   pair_token   = (int*)(ws + 164352);                // 49152
        int*   slot_of      = (int*)(ws + 213504);                // 32768
        unsigned short* xb  = (unsigned short*)(ws + 262144);     // 2 MB
        unsigned short* act_s  = (unsigned short*)(ws + 2359296);    // 12.6 MB
        unsigned short* act_sh = (unsigned short*)(ws + 14942208);   // 4 MB
        unsigned short* BG  = (unsigned short*)(ws + 19136512);      // 32 MB
        unsigned short* BU  = (unsigned short*)(ws + 52690944);      // 32 MB
        unsigned short* SG  = (unsigned short*)(ws + 86245376);      // 4 MB
        unsigned short* SU  = (unsigned short*)(ws + 90439680);      // 4 MB
        unsigned short* BDs = (unsigned short*)(ws + 94633984);      // 32 MB
        unsigned short* BSD = (unsigned short*)(ws + 128188416);     // 4 MB
        // partials alias dead BG/BU region (BG/BU only read by gateup_u)
        float* pairpart     = (float*)(ws + 19136512);               // 50.33 MB
        float* shpart       = (float*)(ws + 69468160);               // 16 MB, ends 86245376

        cvt_x_kernel<<<1024, 256, 0, stream>>>(x, xb);
        routing_kernel<<<256, 256, 0, stream>>>(x, gate_w, e_bias, combine, topk);
        listbuild_kernel<<<1, 1024, 0, stream>>>(topk, meta, pair_token, slot_of);
        tcvt_all<<<13824, 256, 0, stream>>>(w_gate, w_up, ws_gate, ws_up, w_down, ws_down,
                                            BG, BU, SG, SU, BDs, BSD);
        gateup_u<<<MAXTILES * 4 + 128, 256, 0, stream>>>(xb, BG, BU, SG, SU, combine,
                                                         pair_token, meta, act_s, act_sh);
        down_u<<<MAXTILES * 8 + 256, 256, 0, stream>>>(act_s, BDs, act_sh, BSD, meta,
                                                       pairpart, shpart);
        final_combine<<<1024, 256, 0, stream>>>(pairpart, shpart, slot_of, out);
    } else {
        float* combine     = (float*)(ws);
        int*   topk        = (int*)(ws + 131072);
        unsigned short* xb = (unsigned short*)(ws + 262144);
        unsigned short* act= (unsigned short*)(ws + 2359296);
        float* partials    = (float*)(ws + 40108032);

        cvt_x_kernel<<<1024, 256, 0, stream>>>(x, xb);
        routing_kernel<<<256, 256, 0, stream>>>(x, gate_w, e_bias, combine, topk);
        gateup_kernel<<<dim3(8, 144), 256, 0, stream>>>(xb, w_gate, w_up, ws_gate, ws_up, combine, act);
        down_kernel<<<dim3(8, 8, 4), 256, 0, stream>>>(act, w_down, ws_down, partials);
        reduce_kernel<<<1024, 256, 0, stream>>>(partials, out);
    }
}